// Round 9
// baseline (656.596 us; speedup 1.0000x reference)
//
#include <hip/hip_runtime.h>
#include <math.h>

#define RR 32
#define V 32768          // RR^3
#define C 240
#define N 16384
#define B 8
#define K2C 480          // 2*C
#define GZ 16            // voxels per group (proven R1 geometry)
#define NGRP 2048        // groups per batch
#define FPAD 488         // fea_s row stride in ushorts
#define EBUF 512         // staged point entries per round

typedef __attribute__((ext_vector_type(8))) short bf16x8;
typedef __attribute__((ext_vector_type(4))) float f32x4;

__device__ __forceinline__ unsigned short f2bf(float x) {
    unsigned u = __float_as_uint(x);
    u += 0x7fffu + ((u >> 16) & 1u);   // RNE, finite inputs
    return (unsigned short)(u >> 16);
}

// ---------- prep: transpose (blocks 0..4095) + hist/ctrs zero + w->bf16 (4096..4351) + stats (4352..4359) ----------
__global__ __launch_bounds__(256) void prep_kernel(const float* __restrict__ feat,
                                                   unsigned short* __restrict__ featT,
                                                   const float* __restrict__ coords,
                                                   float* __restrict__ stats,
                                                   int* __restrict__ hist,
                                                   int* __restrict__ ctrs,
                                                   const float* __restrict__ w,
                                                   unsigned short* __restrict__ w_bf) {
    __shared__ float t[C][33];
    int blk = blockIdx.x;
    int tid = threadIdx.x;
    if (blk < 4096) {
        // ---- transpose role: features [B][C][N] fp32 -> featT [B][N][C] bf16 ----
        int bx = blk & 511, b = blk >> 9;
        int n0 = bx * 32;
        int l = tid;
        const float* fb = feat + (size_t)b * C * N;
        unsigned short* fTb = featT + (size_t)b * N * C;
        int nl = l & 31, cs = l >> 5;   // 8 c-rows per pass
#pragma unroll
        for (int p = 0; p < 30; ++p) {
            int c = p * 8 + cs;
            t[c][nl] = fb[(size_t)c * N + n0 + nl];
        }
        __syncthreads();
        int ci = l & 127;               // uint (2-channel) index, <120 active
        int nh = l >> 7;                // 2 n-rows per pass
#pragma unroll
        for (int p = 0; p < 16; ++p) {
            int n = 2 * p + nh;
            if (ci < 120) {
                unsigned lo = f2bf(t[2 * ci][n]);
                unsigned hi = f2bf(t[2 * ci + 1][n]);
                *(unsigned*)&fTb[(size_t)(n0 + n) * C + 2 * ci] = lo | (hi << 16);
            }
        }
        return;
    }
    if (blk < 4352) {
        // ---- zero hist + counters, convert conv_w ----
        int tt = (blk - 4096) * 256 + tid;       // 65536 threads
        int4 z4 = {0, 0, 0, 0};
        ((int4*)hist)[tt] = z4;                  // B*V ints = 65536 int4 exactly
        if (tt < 57600) {                        // 240*480/2 packed converts
            unsigned lo = f2bf(w[2 * tt]);
            unsigned hi = f2bf(w[2 * tt + 1]);
            ((unsigned*)w_bf)[tt] = lo | (hi << 16);
        }
        if (tt < 4) ctrs[tt] = 0;                // [0]=ncomp [1]=nfill [2]=comp steal [3]=fill steal
        return;
    }
    // ---- stats role ----
    int b = blk - 4352;
    const float* cb = coords + (size_t)b * 3 * N;
    __shared__ float red[256];
    float m[3];
    for (int d = 0; d < 3; ++d) {
        float s = 0.f;
        for (int n = tid; n < N; n += 256) s += cb[d * N + n];
        red[tid] = s; __syncthreads();
        for (int w2 = 128; w2 > 0; w2 >>= 1) { if (tid < w2) red[tid] += red[tid + w2]; __syncthreads(); }
        m[d] = red[0] / (float)N;
        __syncthreads();
    }
    float mx = 0.f;
    for (int n = tid; n < N; n += 256) {
        float dx = cb[0 * N + n] - m[0];
        float dy = cb[1 * N + n] - m[1];
        float dz = cb[2 * N + n] - m[2];
        mx = fmaxf(mx, dx * dx + dy * dy + dz * dz);
    }
    red[tid] = mx; __syncthreads();
    for (int w2 = 128; w2 > 0; w2 >>= 1) { if (tid < w2) red[tid] = fmaxf(red[tid], red[tid + w2]); __syncthreads(); }
    if (tid == 0) {
        stats[b * 4 + 0] = m[0];
        stats[b * 4 + 1] = m[1];
        stats[b * 4 + 2] = m[2];
        stats[b * 4 + 3] = 2.f * sqrtf(red[0]);
    }
}

// ---------- nc (output 2) + flat voxel idx + per-voxel histogram ----------
__global__ __launch_bounds__(256) void nc_idx_kernel(const float* __restrict__ coords,
                                                     const float* __restrict__ stats,
                                                     float* __restrict__ nc_out,
                                                     int* __restrict__ idxbuf,
                                                     int* __restrict__ hist) {
    int t = blockIdx.x * 256 + threadIdx.x;   // over B*N
    int b = t >> 14;
    int n = t & (N - 1);
    float denom = stats[b * 4 + 3];
    int v[3];
#pragma unroll
    for (int d = 0; d < 3; ++d) {
        float x = coords[((size_t)b * 3 + d) * N + n];
        float t0 = (x - stats[b * 4 + d]) / denom + 0.5f;
        t0 = t0 * (float)RR;
        t0 = fminf(fmaxf(t0, 0.f), (float)(RR - 1));
        nc_out[((size_t)b * 3 + d) * N + n] = t0;
        v[d] = (int)rintf(t0);   // round half to even == jnp.round
    }
    int iv = v[0] * (RR * RR) + v[1] * RR + v[2];
    idxbuf[t] = iv;
    atomicAdd(hist + b * V + iv, 1);
}

// ---------- exclusive prefix over V=32768 voxels per batch + FLAT global worklists ----------
// gwl: non-empty 16-groups (compute), cross-batch. gfl: empty groups for y0 fill
// (bit14 = both halves of a 32-col empty -> one merged entry). entry = b<<11 | group.
__global__ __launch_bounds__(1024) void prefix_kernel(const int* __restrict__ hist,
                                                      int* __restrict__ starts,
                                                      int* __restrict__ cursor,
                                                      int* __restrict__ gwl,
                                                      int* __restrict__ gfl,
                                                      int* __restrict__ ctrs) {
    __shared__ int part[1024];
    int b = blockIdx.x, t = threadIdx.x;
    int base = b * V + t * 32;
    const int4* hp = (const int4*)(hist + base);
    int4 h[8];
#pragma unroll
    for (int j = 0; j < 8; ++j) h[j] = hp[j];
    int pcA = h[0].x + h[0].y + h[0].z + h[0].w + h[1].x + h[1].y + h[1].z + h[1].w
            + h[2].x + h[2].y + h[2].z + h[2].w + h[3].x + h[3].y + h[3].z + h[3].w;
    int pcB = h[4].x + h[4].y + h[4].z + h[4].w + h[5].x + h[5].y + h[5].z + h[5].w
            + h[6].x + h[6].y + h[6].z + h[6].w + h[7].x + h[7].y + h[7].z + h[7].w;
    int s = pcA + pcB;
    if (pcA > 0) { int p = atomicAdd(ctrs + 0, 1); gwl[p] = (b << 11) | (2 * t); }
    if (pcB > 0) { int p = atomicAdd(ctrs + 0, 1); gwl[p] = (b << 11) | (2 * t + 1); }
    if (pcA == 0 && pcB == 0) { int q = atomicAdd(ctrs + 1, 1); gfl[q] = 0x4000 | (b << 11) | (2 * t); }
    else if (pcA == 0)        { int q = atomicAdd(ctrs + 1, 1); gfl[q] = (b << 11) | (2 * t); }
    else if (pcB == 0)        { int q = atomicAdd(ctrs + 1, 1); gfl[q] = (b << 11) | (2 * t + 1); }
    part[t] = s; __syncthreads();
    for (int off = 1; off < 1024; off <<= 1) {
        int x = (t >= off) ? part[t - off] : 0;
        __syncthreads();
        part[t] += x;
        __syncthreads();
    }
    int run = part[t] - s;   // exclusive
    int4* sp = (int4*)(starts + base);
    int4* cp = (int4*)(cursor + base);
#pragma unroll
    for (int j = 0; j < 8; ++j) {
        int4 o;
        o.x = run; run += h[j].x;
        o.y = run; run += h[j].y;
        o.z = run; run += h[j].z;
        o.w = run; run += h[j].w;
        sp[j] = o; cp[j] = o;
    }
}

// ---------- scatter point ids into voxel-sorted order ----------
__global__ __launch_bounds__(256) void plist_kernel(const int* __restrict__ idxbuf,
                                                    int* __restrict__ cursor,
                                                    int* __restrict__ ptlist) {
    int t = blockIdx.x * 256 + threadIdx.x;   // over B*N
    int b = t >> 14;
    int n = t & (N - 1);
    int iv = idxbuf[t];
    int pos = atomicAdd(cursor + b * V + iv, 1);
    ptlist[(b << 14) + pos] = (n << 5) | (iv & 31);
}

// ---------- 2-deep pipelined 2-channel gather (u32 loads, R0-proven unpack) ----------
#define PF2(U, Z0, Z1, basei)                                               \
    {                                                                       \
        Z0 = 0u; Z1 = 0u;                                                   \
        _Pragma("unroll")                                                   \
        for (int j = 0; j < 16; ++j) {                                      \
            int idx2 = basei + j; idx2 = (idx2 < mm) ? idx2 : mm - 1;       \
            int e = ebg[idx2];                                              \
            U[j] = *(const unsigned*)&fT[(size_t)(e >> 5) * C + cc2];       \
            unsigned zz = (unsigned)(e & 15);                               \
            if (j < 8) Z0 |= zz << (4 * j); else Z1 |= zz << (4 * (j - 8)); \
        }                                                                   \
    }

#define PR2(U, Z0, Z1, basei)                                               \
    {                                                                       \
        _Pragma("unroll")                                                   \
        for (int j = 0; j < 16; ++j) {                                      \
            if (basei + j < mm) {                                           \
                int zj = (int)(((j < 8 ? Z0 : Z1) >> (4 * (j & 7))) & 15u); \
                if (zj != curz) {                                           \
                    if (curz >= 0) {                                        \
                        float rc = rcp_s[rb + curz];                        \
                        *(unsigned*)&fea_s[rb + curz][cc2] =                \
                            (unsigned)f2bf(mx0) | ((unsigned)f2bf(mx1) << 16); \
                        *(unsigned*)&fea_s[rb + curz][C + cc2] =            \
                            (unsigned)f2bf(s0 * rc) | ((unsigned)f2bf(s1 * rc) << 16); \
                    }                                                       \
                    curz = zj; s0 = s1 = 0.f; mx0 = mx1 = -INFINITY;        \
                }                                                           \
                unsigned u = U[j];                                          \
                float flo = __uint_as_float(u << 16);                       \
                float fhi = __uint_as_float(u & 0xffff0000u);               \
                s0 += flo; s1 += fhi;                                       \
                mx0 = fmaxf(mx0, flo); mx1 = fmaxf(mx1, fhi);               \
            }                                                               \
        }                                                                   \
    }

// ---------- persistent work-stealing column: paired reduce + MFMA, then fill drain ----------
// 1024 persistent blocks (= 4/CU LDS cap). Pairs may mix batches (weights shared).
__global__ __launch_bounds__(256, 4) void column_kernel(
    const unsigned short* __restrict__ featT,   // [B][N][C] bf16
    const int* __restrict__ ptlist,
    const int* __restrict__ starts,
    const int* __restrict__ hist,
    const unsigned short* __restrict__ w_bf,    // [240][480] bf16
    const float* __restrict__ cbias, const float* __restrict__ gamma,
    const float* __restrict__ beta, const float* __restrict__ mean,
    const float* __restrict__ var,
    const int* __restrict__ gwl, const int* __restrict__ gfl,
    int* __restrict__ ctrs,
    float* __restrict__ out) {
    const int tid = threadIdx.x;

    __shared__ float A_s[C], B_s[C], y0_s[C], rcp_s[2 * GZ];
    __shared__ unsigned short fea_s[2 * GZ][FPAD];   // rows 0-15: g0, 16-31: g1
    __shared__ int cnt_s[2 * GZ];
    __shared__ int ebuf0[EBUF], ebuf1[EBUF];
    __shared__ int grab_s;

    if (tid < C) {
        float sc = gamma[tid] * rsqrtf(var[tid] + 1e-5f);
        A_s[tid] = sc;
        float b0 = (cbias[tid] - mean[tid]) * sc + beta[tid];
        B_s[tid] = b0;
        y0_s[tid] = b0 / (1.f + __expf(-b0));   // swish of zero-feature output
    }
    const int ncomp = ctrs[0];
    const int nfill = ctrs[1];

    const int lane = tid & 63, wave = tid >> 6;
    const int grp = wave >> 1;          // wave-pair -> group
    const int rb = grp << 4;            // fea row base
    const int cc = tid & 127;           // channel-pair index within group
    const int cc2 = cc << 1;
    const bool act = cc < 120;
    const int mcnt = (wave == 3) ? 3 : 4;      // 15 o-tiles split 4/4/4/3
    const int zl = lane & 15;
    const int koff = (lane >> 4) * 8;
    const int rbase = (lane >> 4) * 4;

    // ---------- compute-pair steal loop ----------
    for (;;) {
        __syncthreads();                       // protects grab_s + prior-iter shared reads
        if (tid == 0) grab_s = atomicAdd(ctrs + 2, 2);
        __syncthreads();
        const int idx = grab_s;
        if (idx >= ncomp) break;               // uniform
        const int e0 = gwl[idx];
        const bool has1 = (idx + 1) < ncomp;
        const int e1 = has1 ? gwl[idx + 1] : e0;
        const int b0i = (e0 >> 11) & 7, b1i = (e1 >> 11) & 7;
        const int v00 = (e0 & 0x7ff) * GZ, v01 = (e1 & 0x7ff) * GZ;

        if (tid < GZ) {
            int c0 = hist[b0i * V + v00 + tid];
            cnt_s[tid] = c0; rcp_s[tid] = 1.f / (float)max(c0, 1);
        } else if (tid < 2 * GZ) {
            int c0 = hist[b1i * V + v01 + (tid - GZ)];
            cnt_s[tid] = c0; rcp_s[tid] = 1.f / (float)max(c0, 1);
        }
        // zero fea (covers empty voxels: max->0, avg->0)
        for (int i = tid; i < 2 * GZ * FPAD / 2; i += 256) ((unsigned*)fea_s)[i] = 0u;
        __syncthreads();

        int pc0 = 0, pc1 = 0;
#pragma unroll
        for (int z = 0; z < GZ; ++z) { pc0 += cnt_s[z]; pc1 += cnt_s[GZ + z]; }

        const unsigned short* fT = featT + (size_t)(grp ? b1i : b0i) * N * C;
        const int* pl0 = ptlist + (b0i << 14) + starts[b0i * V + v00];
        const int* pl1 = ptlist + (b1i << 14) + starts[b1i * V + v01];
        const int* ebg = grp ? ebuf1 : ebuf0;

        // ---- concurrent 2-channel streams (sorted by z) ----
        float s0 = 0.f, s1 = 0.f, mx0 = -INFINITY, mx1 = -INFINITY;
        int curz = -1;
        const int pcmax = max(pc0, pc1);
        for (int base = 0; base < pcmax; base += EBUF) {
            int mm0 = min(EBUF, pc0 - base);
            int mm1 = min(EBUF, pc1 - base);
            __syncthreads();
            for (int i = tid; i < mm0; i += 256) ebuf0[i] = pl0[base + i];   // coalesced stage
            for (int i = tid; i < mm1; i += 256) ebuf1[i] = pl1[base + i];
            __syncthreads();
            int mm = grp ? mm1 : mm0;
            if (act && mm > 0) {
                unsigned uA[16], uB[16];
                unsigned zA0 = 0, zA1 = 0, zB0 = 0, zB1 = 0;
                PF2(uA, zA0, zA1, 0);
                for (int i0 = 0; i0 < mm; i0 += 32) {
                    if (i0 + 16 < mm) PF2(uB, zB0, zB1, i0 + 16);
                    PR2(uA, zA0, zA1, i0);
                    if (i0 + 32 < mm) PF2(uA, zA0, zA1, i0 + 32);
                    PR2(uB, zB0, zB1, i0 + 16);
                }
            }
        }
        if (act && curz >= 0) {
            float rc = rcp_s[rb + curz];
            *(unsigned*)&fea_s[rb + curz][cc2] = (unsigned)f2bf(mx0) | ((unsigned)f2bf(mx1) << 16);
            *(unsigned*)&fea_s[rb + curz][C + cc2] = (unsigned)f2bf(s0 * rc) | ((unsigned)f2bf(s1 * rc) << 16);
        }
        __syncthreads();

        // ---- MFMA: D[o][z] = sum_k w[o][k] * fea[z][k]; afr shared across the two groups ----
        f32x4 acc0[4], acc1[4];
#pragma unroll
        for (int i = 0; i < 4; ++i) { acc0[i] = (f32x4){0.f, 0.f, 0.f, 0.f}; acc1[i] = (f32x4){0.f, 0.f, 0.f, 0.f}; }

#pragma unroll
        for (int kc = 0; kc < 15; ++kc) {
            const int kg = kc * 32 + koff;
            bf16x8 bfr0 = *(const bf16x8*)&fea_s[zl][kg];
            bf16x8 bfr1 = *(const bf16x8*)&fea_s[GZ + zl][kg];
            const unsigned short* wp = w_bf + (size_t)(wave * 64 + zl) * K2C + kg;
#pragma unroll
            for (int mt = 0; mt < 4; ++mt) {
                if (mt < mcnt) {
                    bf16x8 afr = *(const bf16x8*)(wp + (size_t)mt * 16 * K2C);
                    acc0[mt] = __builtin_amdgcn_mfma_f32_16x16x32_bf16(afr, bfr0, acc0[mt], 0, 0, 0);
                    acc1[mt] = __builtin_amdgcn_mfma_f32_16x16x32_bf16(afr, bfr1, acc1[mt], 0, 0, 0);
                }
            }
        }

        float* outb0 = out + (size_t)b0i * C * V;
        float* outb1 = out + (size_t)b1i * C * V;
        const int vv0 = v00 + zl, vv1 = v01 + zl;
#pragma unroll
        for (int mt = 0; mt < 4; ++mt) {
            if (mt < mcnt) {
#pragma unroll
                for (int r = 0; r < 4; ++r) {
                    int o = (wave * 4 + mt) * 16 + rbase + r;
                    float y = acc0[mt][r] * A_s[o] + B_s[o];
                    y = y / (1.f + __expf(-y));
                    outb0[(size_t)o * V + vv0] = y;
                    if (has1) {
                        float y1 = acc1[mt][r] * A_s[o] + B_s[o];
                        y1 = y1 / (1.f + __expf(-y1));
                        outb1[(size_t)o * V + vv1] = y1;
                    }
                }
            }
        }
    }

    // ---------- fill steal loop (y0 writes hide under other blocks' compute) ----------
    for (;;) {
        __syncthreads();
        if (tid == 0) grab_s = atomicAdd(ctrs + 3, 1);
        __syncthreads();
        const int idx = grab_s;
        if (idx >= nfill) break;               // uniform
        const int e = gfl[idx];
        const int bb = (e >> 11) & 7;
        const int v0 = (e & 0x7ff) * GZ;
        float* outb = out + (size_t)bb * C * V;
        if (e & 0x4000) {       // both halves of the 32-z column empty: 128-B line stores
            for (int i = tid; i < C * 8; i += 256) {
                int o = i >> 3, q = i & 7;
                float y = y0_s[o];
                float4 f4 = {y, y, y, y};
                *(float4*)&outb[(size_t)o * V + v0 + q * 4] = f4;
            }
        } else {                // single empty 16-group
            for (int i = tid; i < C * 4; i += 256) {
                int o = i >> 2, q = i & 3;
                float y = y0_s[o];
                float4 f4 = {y, y, y, y};
                *(float4*)&outb[(size_t)o * V + v0 + q * 4] = f4;
            }
        }
    }
}

extern "C" void kernel_launch(void* const* d_in, const int* in_sizes, int n_in,
                              void* d_out, int out_size, void* d_ws, size_t ws_size,
                              hipStream_t stream) {
    const float* features = (const float*)d_in[0];  // [B][C][N]
    const float* coords   = (const float*)d_in[1];  // [B][3][N]
    const float* conv_w   = (const float*)d_in[2];  // [240][480]
    const float* conv_b   = (const float*)d_in[3];
    const float* gamma    = (const float*)d_in[4];
    const float* beta     = (const float*)d_in[5];
    const float* mean     = (const float*)d_in[6];
    const float* var      = (const float*)d_in[7];

    float* out    = (float*)d_out;                    // [B][C][V]
    float* nc_out = out + (size_t)B * C * V;          // [B][3][N]

    char* ws = (char*)d_ws;
    size_t off = 0;
    auto carve = [&](size_t bytes) { char* p = ws + off; off += (bytes + 255) & ~(size_t)255; return p; };
    int*            hist   = (int*)carve((size_t)B * V * 4);          // 1 MB
    float*          stats  = (float*)carve(B * 4 * 4);
    int*            idxbuf = (int*)carve((size_t)B * N * 4);
    int*            starts = (int*)carve((size_t)B * V * 4);
    int*            cursor = (int*)carve((size_t)B * V * 4);
    int*            ptlist = (int*)carve((size_t)B * N * 4);
    int*            gwl    = (int*)carve((size_t)B * NGRP * 4);       // flat compute list
    int*            gfl    = (int*)carve((size_t)B * NGRP * 4);       // flat fill list
    int*            ctrs   = (int*)carve(4 * 4);                      // counts + steal cursors
    unsigned short* w_bf   = (unsigned short*)carve((size_t)C * K2C * 2);
    unsigned short* featT  = (unsigned short*)carve((size_t)B * N * C * 2);  // 63 MB
    (void)off;

    prep_kernel<<<4360, 256, 0, stream>>>(features, featT, coords, stats, hist, ctrs, conv_w, w_bf);
    nc_idx_kernel<<<(B * N) / 256, 256, 0, stream>>>(coords, stats, nc_out, idxbuf, hist);
    prefix_kernel<<<B, 1024, 0, stream>>>(hist, starts, cursor, gwl, gfl, ctrs);
    plist_kernel<<<(B * N) / 256, 256, 0, stream>>>(idxbuf, cursor, ptlist);
    column_kernel<<<1024, 256, 0, stream>>>(
        featT, ptlist, starts, hist, w_bf,
        conv_b, gamma, beta, mean, var, gwl, gfl, ctrs, out);
    (void)in_sizes; (void)n_in; (void)out_size;
}

// Round 10
// 547.219 us; speedup vs baseline: 1.1999x; 1.1999x over previous
//
#include <hip/hip_runtime.h>
#include <math.h>

#define RR 32
#define V 32768          // RR^3
#define C 240
#define N 16384
#define B 8
#define K2C 480          // 2*C
#define GZ 16            // voxels per group (proven R1 geometry)
#define NGRP 2048        // groups per batch
#define FPAD 488         // fea_s row stride in ushorts
#define EBUF 512         // staged point entries per round

typedef __attribute__((ext_vector_type(8))) short bf16x8;
typedef __attribute__((ext_vector_type(4))) float f32x4;

__device__ __forceinline__ unsigned short f2bf(float x) {
    unsigned u = __float_as_uint(x);
    u += 0x7fffu + ((u >> 16) & 1u);   // RNE, finite inputs
    return (unsigned short)(u >> 16);
}

// ---------- prep: transpose (blocks 0..4095) + hist/wlcnt zero + w->bf16 (4096..4351) + stats (4352..4359) ----------
__global__ __launch_bounds__(256) void prep_kernel(const float* __restrict__ feat,
                                                   unsigned short* __restrict__ featT,
                                                   const float* __restrict__ coords,
                                                   float* __restrict__ stats,
                                                   int* __restrict__ hist,
                                                   int* __restrict__ wlcnt,
                                                   const float* __restrict__ w,
                                                   unsigned short* __restrict__ w_bf) {
    __shared__ float t[C][33];
    int blk = blockIdx.x;
    int tid = threadIdx.x;
    if (blk < 4096) {
        // ---- transpose role: features [B][C][N] fp32 -> featT [B][N][C] bf16 ----
        int bx = blk & 511, b = blk >> 9;
        int n0 = bx * 32;
        int l = tid;
        const float* fb = feat + (size_t)b * C * N;
        unsigned short* fTb = featT + (size_t)b * N * C;
        int nl = l & 31, cs = l >> 5;   // 8 c-rows per pass
#pragma unroll
        for (int p = 0; p < 30; ++p) {
            int c = p * 8 + cs;
            t[c][nl] = fb[(size_t)c * N + n0 + nl];
        }
        __syncthreads();
        int ci = l & 127;               // uint (2-channel) index, <120 active
        int nh = l >> 7;                // 2 n-rows per pass
#pragma unroll
        for (int p = 0; p < 16; ++p) {
            int n = 2 * p + nh;
            if (ci < 120) {
                unsigned lo = f2bf(t[2 * ci][n]);
                unsigned hi = f2bf(t[2 * ci + 1][n]);
                *(unsigned*)&fTb[(size_t)(n0 + n) * C + 2 * ci] = lo | (hi << 16);
            }
        }
        return;
    }
    if (blk < 4352) {
        // ---- zero hist + wlcnt, convert conv_w ----
        int tt = (blk - 4096) * 256 + tid;       // 65536 threads
        int4 z4 = {0, 0, 0, 0};
        ((int4*)hist)[tt] = z4;                  // B*V ints = 65536 int4 exactly
        if (tt < 57600) {                        // 240*480/2 packed converts
            unsigned lo = f2bf(w[2 * tt]);
            unsigned hi = f2bf(w[2 * tt + 1]);
            ((unsigned*)w_bf)[tt] = lo | (hi << 16);
        }
        if (tt < 2 * B) wlcnt[tt] = 0;           // front + back counters
        return;
    }
    // ---- stats role ----
    int b = blk - 4352;
    const float* cb = coords + (size_t)b * 3 * N;
    __shared__ float red[256];
    float m[3];
    for (int d = 0; d < 3; ++d) {
        float s = 0.f;
        for (int n = tid; n < N; n += 256) s += cb[d * N + n];
        red[tid] = s; __syncthreads();
        for (int w2 = 128; w2 > 0; w2 >>= 1) { if (tid < w2) red[tid] += red[tid + w2]; __syncthreads(); }
        m[d] = red[0] / (float)N;
        __syncthreads();
    }
    float mx = 0.f;
    for (int n = tid; n < N; n += 256) {
        float dx = cb[0 * N + n] - m[0];
        float dy = cb[1 * N + n] - m[1];
        float dz = cb[2 * N + n] - m[2];
        mx = fmaxf(mx, dx * dx + dy * dy + dz * dz);
    }
    red[tid] = mx; __syncthreads();
    for (int w2 = 128; w2 > 0; w2 >>= 1) { if (tid < w2) red[tid] = fmaxf(red[tid], red[tid + w2]); __syncthreads(); }
    if (tid == 0) {
        stats[b * 4 + 0] = m[0];
        stats[b * 4 + 1] = m[1];
        stats[b * 4 + 2] = m[2];
        stats[b * 4 + 3] = 2.f * sqrtf(red[0]);
    }
}

// ---------- nc (output 2) + flat voxel idx + per-voxel histogram ----------
__global__ __launch_bounds__(256) void nc_idx_kernel(const float* __restrict__ coords,
                                                     const float* __restrict__ stats,
                                                     float* __restrict__ nc_out,
                                                     int* __restrict__ idxbuf,
                                                     int* __restrict__ hist) {
    int t = blockIdx.x * 256 + threadIdx.x;   // over B*N
    int b = t >> 14;
    int n = t & (N - 1);
    float denom = stats[b * 4 + 3];
    int v[3];
#pragma unroll
    for (int d = 0; d < 3; ++d) {
        float x = coords[((size_t)b * 3 + d) * N + n];
        float t0 = (x - stats[b * 4 + d]) / denom + 0.5f;
        t0 = t0 * (float)RR;
        t0 = fminf(fmaxf(t0, 0.f), (float)(RR - 1));
        nc_out[((size_t)b * 3 + d) * N + n] = t0;
        v[d] = (int)rintf(t0);   // round half to even == jnp.round
    }
    int iv = v[0] * (RR * RR) + v[1] * RR + v[2];
    idxbuf[t] = iv;
    atomicAdd(hist + b * V + iv, 1);
}

// ---------- exclusive prefix over V=32768 voxels per batch + DETERMINISTIC dual worklist ----------
// Scan-compacted (no atomics): wl front = non-empty 16-groups sorted by group id
// (adjacent pairs are usually the two halves of one 32-column -> full-line write
// combining in column_kernel); wl back = empty groups sorted (bit16 = merged column).
__global__ __launch_bounds__(1024) void prefix_kernel(const int* __restrict__ hist,
                                                      int* __restrict__ starts,
                                                      int* __restrict__ cursor,
                                                      int* __restrict__ wl,
                                                      int* __restrict__ wlcnt) {
    __shared__ int part[1024];
    int b = blockIdx.x, t = threadIdx.x;
    int base = b * V + t * 32;
    const int4* hp = (const int4*)(hist + base);
    int4 h[8];
#pragma unroll
    for (int j = 0; j < 8; ++j) h[j] = hp[j];
    int pcA = h[0].x + h[0].y + h[0].z + h[0].w + h[1].x + h[1].y + h[1].z + h[1].w
            + h[2].x + h[2].y + h[2].z + h[2].w + h[3].x + h[3].y + h[3].z + h[3].w;
    int pcB = h[4].x + h[4].y + h[4].z + h[4].w + h[5].x + h[5].y + h[5].z + h[5].w
            + h[6].x + h[6].y + h[6].z + h[6].w + h[7].x + h[7].y + h[7].z + h[7].w;
    int s = pcA + pcB;
    // ---- scan 1: point counts -> starts/cursor ----
    part[t] = s; __syncthreads();
    for (int off = 1; off < 1024; off <<= 1) {
        int x = (t >= off) ? part[t - off] : 0;
        __syncthreads();
        part[t] += x;
        __syncthreads();
    }
    int run = part[t] - s;   // exclusive
    int4* sp = (int4*)(starts + base);
    int4* cp = (int4*)(cursor + base);
#pragma unroll
    for (int j = 0; j < 8; ++j) {
        int4 o;
        o.x = run; run += h[j].x;
        o.y = run; run += h[j].y;
        o.z = run; run += h[j].z;
        o.w = run; run += h[j].w;
        sp[j] = o; cp[j] = o;
    }
    // ---- scan 2: compute-entry positions (ordered compaction) ----
    int cf = (pcA > 0 ? 1 : 0) + (pcB > 0 ? 1 : 0);
    __syncthreads();
    part[t] = cf; __syncthreads();
    for (int off = 1; off < 1024; off <<= 1) {
        int x = (t >= off) ? part[t - off] : 0;
        __syncthreads();
        part[t] += x;
        __syncthreads();
    }
    int cpos = part[t] - cf;
    if (pcA > 0) wl[b * NGRP + cpos] = 2 * t;
    if (pcB > 0) wl[b * NGRP + cpos + (pcA > 0 ? 1 : 0)] = 2 * t + 1;
    if (t == 1023) wlcnt[b] = cpos + cf;
    // ---- scan 3: fill-entry positions (ordered, written from the back) ----
    int ff = (pcA == 0 || pcB == 0) ? 1 : 0;
    __syncthreads();
    part[t] = ff; __syncthreads();
    for (int off = 1; off < 1024; off <<= 1) {
        int x = (t >= off) ? part[t - off] : 0;
        __syncthreads();
        part[t] += x;
        __syncthreads();
    }
    int fpos = part[t] - ff;
    if (pcA == 0 && pcB == 0) wl[b * NGRP + NGRP - 1 - fpos] = (2 * t) | 0x10000;
    else if (pcA == 0)        wl[b * NGRP + NGRP - 1 - fpos] = 2 * t;
    else if (pcB == 0)        wl[b * NGRP + NGRP - 1 - fpos] = 2 * t + 1;
    if (t == 1023) wlcnt[B + b] = fpos + ff;
}

// ---------- scatter point ids into voxel-sorted order ----------
__global__ __launch_bounds__(256) void plist_kernel(const int* __restrict__ idxbuf,
                                                    int* __restrict__ cursor,
                                                    int* __restrict__ ptlist) {
    int t = blockIdx.x * 256 + threadIdx.x;   // over B*N
    int b = t >> 14;
    int n = t & (N - 1);
    int iv = idxbuf[t];
    int pos = atomicAdd(cursor + b * V + iv, 1);
    ptlist[(b << 14) + pos] = (n << 5) | (iv & 31);
}

// ---------- 2-deep pipelined 2-channel gather (u32 loads, R0-proven unpack) ----------
#define PF2(U, Z0, Z1, basei)                                               \
    {                                                                       \
        Z0 = 0u; Z1 = 0u;                                                   \
        _Pragma("unroll")                                                   \
        for (int j = 0; j < 16; ++j) {                                      \
            int idx = basei + j; idx = (idx < mm) ? idx : mm - 1;           \
            int e = ebg[idx];                                               \
            U[j] = *(const unsigned*)&fT[(size_t)(e >> 5) * C + cc2];       \
            unsigned zz = (unsigned)(e & 15);                               \
            if (j < 8) Z0 |= zz << (4 * j); else Z1 |= zz << (4 * (j - 8)); \
        }                                                                   \
    }

#define PR2(U, Z0, Z1, basei)                                               \
    {                                                                       \
        _Pragma("unroll")                                                   \
        for (int j = 0; j < 16; ++j) {                                      \
            if (basei + j < mm) {                                           \
                int zj = (int)(((j < 8 ? Z0 : Z1) >> (4 * (j & 7))) & 15u); \
                if (zj != curz) {                                           \
                    if (curz >= 0) {                                        \
                        float rc = rcp_s[rb + curz];                        \
                        *(unsigned*)&fea_s[rb + curz][cc2] =                \
                            (unsigned)f2bf(mx0) | ((unsigned)f2bf(mx1) << 16); \
                        *(unsigned*)&fea_s[rb + curz][C + cc2] =            \
                            (unsigned)f2bf(s0 * rc) | ((unsigned)f2bf(s1 * rc) << 16); \
                    }                                                       \
                    curz = zj; s0 = s1 = 0.f; mx0 = mx1 = -INFINITY;        \
                }                                                           \
                unsigned u = U[j];                                          \
                float flo = __uint_as_float(u << 16);                       \
                float fhi = __uint_as_float(u & 0xffff0000u);               \
                s0 += flo; s1 += fhi;                                       \
                mx0 = fmaxf(mx0, flo); mx1 = fmaxf(mx1, fhi);               \
            }                                                               \
        }                                                                   \
    }

// ---------- fused PAIRED reduce + bf16 MFMA + BN + swish (dual worklist) ----------
// Waves 0-1 stream group 0, waves 2-3 stream group 1 CONCURRENTLY; each thread
// gathers a channel PAIR (u32). One weight fragment still feeds both groups' MFMAs.
// Ordered worklist -> pairs are usually both halves of one 32-column.
__global__ __launch_bounds__(256, 4) void column_kernel(
    const unsigned short* __restrict__ featT,   // [B][N][C] bf16
    const int* __restrict__ ptlist,
    const int* __restrict__ starts,
    const int* __restrict__ hist,
    const unsigned short* __restrict__ w_bf,    // [240][480] bf16
    const float* __restrict__ cbias, const float* __restrict__ gamma,
    const float* __restrict__ beta, const float* __restrict__ mean,
    const float* __restrict__ var,
    const int* __restrict__ wl, const int* __restrict__ wlcnt,
    float* __restrict__ out) {
    const int bx = blockIdx.x, b = blockIdx.y;
    const int nw = wlcnt[b];
    const int npair = (nw + 1) >> 1;
    const int ntot = npair + wlcnt[B + b];
    if (bx >= ntot) return;                     // uniform per block
    const bool isfill = (bx >= npair);
    const int tid = threadIdx.x;
    float* outb = out + (size_t)b * C * V;

    __shared__ float A_s[C], B_s[C], y0_s[C], rcp_s[2 * GZ];
    __shared__ unsigned short fea_s[2 * GZ][FPAD];   // rows 0-15: g0, 16-31: g1
    __shared__ int cnt_s[2 * GZ];
    __shared__ int ebuf0[EBUF], ebuf1[EBUF];

    int wle0, wle1 = 0;
    bool has1 = false;
    if (isfill) {
        wle0 = wl[b * NGRP + NGRP - 1 - (bx - npair)];
    } else {
        wle0 = wl[b * NGRP + 2 * bx];
        has1 = (2 * bx + 1) < nw;
        wle1 = has1 ? wl[b * NGRP + 2 * bx + 1] : wle0;
    }
    const int v00 = (wle0 & 0xffff) * GZ;
    const int v01 = (wle1 & 0xffff) * GZ;

    if (tid < C) {
        float sc = gamma[tid] * rsqrtf(var[tid] + 1e-5f);
        A_s[tid] = sc;
        float b0 = (cbias[tid] - mean[tid]) * sc + beta[tid];
        B_s[tid] = b0;
        y0_s[tid] = b0 / (1.f + __expf(-b0));   // swish of zero-feature output
    }
    if (!isfill && tid < 2 * GZ) {
        int c0;
        if (tid < GZ) c0 = hist[b * V + v00 + tid];
        else          c0 = has1 ? hist[b * V + v01 + (tid - GZ)] : 0;
        cnt_s[tid] = c0;
        rcp_s[tid] = 1.f / (float)max(c0, 1);
    }
    __syncthreads();

    if (isfill) {   // empty group(s): constant swish vector, writes hidden under other blocks' latency
        if (wle0 >> 16) {       // both halves of the 32-z column empty: 128-B line stores
            for (int i = tid; i < C * 8; i += 256) {
                int o = i >> 3, q = i & 7;
                float y = y0_s[o];
                float4 f4 = {y, y, y, y};
                *(float4*)&outb[(size_t)o * V + v00 + q * 4] = f4;
            }
        } else {                // single empty 16-group
            for (int i = tid; i < C * 4; i += 256) {
                int o = i >> 2, q = i & 3;
                float y = y0_s[o];
                float4 f4 = {y, y, y, y};
                *(float4*)&outb[(size_t)o * V + v00 + q * 4] = f4;
            }
        }
        return;
    }

    int pc0 = 0, pc1 = 0;
#pragma unroll
    for (int z = 0; z < GZ; ++z) { pc0 += cnt_s[z]; pc1 += cnt_s[GZ + z]; }

    // zero fea (covers empty voxels: max->0, avg->0)
    for (int i = tid; i < 2 * GZ * FPAD / 2; i += 256) ((unsigned*)fea_s)[i] = 0u;

    const unsigned short* fT = featT + (size_t)b * N * C;
    const int lane = tid & 63, wave = tid >> 6;
    const int grp = wave >> 1;          // wave-pair -> group
    const int rb = grp << 4;            // fea row base
    const int cc = tid & 127;           // channel-pair index within group
    const int cc2 = cc << 1;
    const bool act = cc < 120;
    const int* pl0 = ptlist + (b << 14) + starts[b * V + v00];
    const int* pl1 = ptlist + (b << 14) + starts[b * V + v01];
    const int* ebg = grp ? ebuf1 : ebuf0;

    // ---- concurrent 2-channel streams (sorted by z) ----
    float s0 = 0.f, s1 = 0.f, mx0 = -INFINITY, mx1 = -INFINITY;
    int curz = -1;
    const int pcmax = max(pc0, pc1);
    for (int base = 0; base < pcmax; base += EBUF) {
        int mm0 = min(EBUF, pc0 - base);
        int mm1 = min(EBUF, pc1 - base);
        __syncthreads();
        for (int i = tid; i < mm0; i += 256) ebuf0[i] = pl0[base + i];   // coalesced stage
        for (int i = tid; i < mm1; i += 256) ebuf1[i] = pl1[base + i];
        __syncthreads();
        int mm = grp ? mm1 : mm0;
        if (act && mm > 0) {
            unsigned uA[16], uB[16];
            unsigned zA0 = 0, zA1 = 0, zB0 = 0, zB1 = 0;
            PF2(uA, zA0, zA1, 0);
            for (int i0 = 0; i0 < mm; i0 += 32) {
                if (i0 + 16 < mm) PF2(uB, zB0, zB1, i0 + 16);
                PR2(uA, zA0, zA1, i0);
                if (i0 + 32 < mm) PF2(uA, zA0, zA1, i0 + 32);
                PR2(uB, zB0, zB1, i0 + 16);
            }
        }
    }
    if (act && curz >= 0) {
        float rc = rcp_s[rb + curz];
        *(unsigned*)&fea_s[rb + curz][cc2] = (unsigned)f2bf(mx0) | ((unsigned)f2bf(mx1) << 16);
        *(unsigned*)&fea_s[rb + curz][C + cc2] = (unsigned)f2bf(s0 * rc) | ((unsigned)f2bf(s1 * rc) << 16);
    }
    __syncthreads();

    // ---- MFMA: D[o][z] = sum_k w[o][k] * fea[z][k]; afr shared across the two groups ----
    const int mcnt = (wave == 3) ? 3 : 4;      // 15 o-tiles split 4/4/4/3
    const int zl = lane & 15;
    const int koff = (lane >> 4) * 8;
    const int rbase = (lane >> 4) * 4;

    f32x4 acc0[4], acc1[4];
#pragma unroll
    for (int i = 0; i < 4; ++i) { acc0[i] = (f32x4){0.f, 0.f, 0.f, 0.f}; acc1[i] = (f32x4){0.f, 0.f, 0.f, 0.f}; }

#pragma unroll
    for (int kc = 0; kc < 15; ++kc) {
        const int kg = kc * 32 + koff;
        bf16x8 bfr0 = *(const bf16x8*)&fea_s[zl][kg];
        bf16x8 bfr1 = *(const bf16x8*)&fea_s[GZ + zl][kg];
        const unsigned short* wp = w_bf + (size_t)(wave * 64 + zl) * K2C + kg;
#pragma unroll
        for (int mt = 0; mt < 4; ++mt) {
            if (mt < mcnt) {
                bf16x8 afr = *(const bf16x8*)(wp + (size_t)mt * 16 * K2C);
                acc0[mt] = __builtin_amdgcn_mfma_f32_16x16x32_bf16(afr, bfr0, acc0[mt], 0, 0, 0);
                acc1[mt] = __builtin_amdgcn_mfma_f32_16x16x32_bf16(afr, bfr1, acc1[mt], 0, 0, 0);
            }
        }
    }

    const int vv0 = v00 + zl, vv1 = v01 + zl;
#pragma unroll
    for (int mt = 0; mt < 4; ++mt) {
        if (mt < mcnt) {
#pragma unroll
            for (int r = 0; r < 4; ++r) {
                int o = (wave * 4 + mt) * 16 + rbase + r;
                float y = acc0[mt][r] * A_s[o] + B_s[o];
                y = y / (1.f + __expf(-y));
                outb[(size_t)o * V + vv0] = y;
                if (has1) {
                    float y1 = acc1[mt][r] * A_s[o] + B_s[o];
                    y1 = y1 / (1.f + __expf(-y1));
                    outb[(size_t)o * V + vv1] = y1;
                }
            }
        }
    }
}

extern "C" void kernel_launch(void* const* d_in, const int* in_sizes, int n_in,
                              void* d_out, int out_size, void* d_ws, size_t ws_size,
                              hipStream_t stream) {
    const float* features = (const float*)d_in[0];  // [B][C][N]
    const float* coords   = (const float*)d_in[1];  // [B][3][N]
    const float* conv_w   = (const float*)d_in[2];  // [240][480]
    const float* conv_b   = (const float*)d_in[3];
    const float* gamma    = (const float*)d_in[4];
    const float* beta     = (const float*)d_in[5];
    const float* mean     = (const float*)d_in[6];
    const float* var      = (const float*)d_in[7];

    float* out    = (float*)d_out;                    // [B][C][V]
    float* nc_out = out + (size_t)B * C * V;          // [B][3][N]

    char* ws = (char*)d_ws;
    size_t off = 0;
    auto carve = [&](size_t bytes) { char* p = ws + off; off += (bytes + 255) & ~(size_t)255; return p; };
    int*            hist   = (int*)carve((size_t)B * V * 4);          // 1 MB
    float*          stats  = (float*)carve(B * 4 * 4);
    int*            idxbuf = (int*)carve((size_t)B * N * 4);
    int*            starts = (int*)carve((size_t)B * V * 4);
    int*            cursor = (int*)carve((size_t)B * V * 4);
    int*            ptlist = (int*)carve((size_t)B * N * 4);
    int*            wl     = (int*)carve((size_t)B * NGRP * 4);       // 64 KB
    int*            wlcnt  = (int*)carve((size_t)2 * B * 4);          // front + back counters
    unsigned short* w_bf   = (unsigned short*)carve((size_t)C * K2C * 2);
    unsigned short* featT  = (unsigned short*)carve((size_t)B * N * C * 2);  // 63 MB
    (void)off;

    prep_kernel<<<4360, 256, 0, stream>>>(features, featT, coords, stats, hist, wlcnt, conv_w, w_bf);
    nc_idx_kernel<<<(B * N) / 256, 256, 0, stream>>>(coords, stats, nc_out, idxbuf, hist);
    prefix_kernel<<<B, 1024, 0, stream>>>(hist, starts, cursor, wl, wlcnt);
    plist_kernel<<<(B * N) / 256, 256, 0, stream>>>(idxbuf, cursor, ptlist);
    column_kernel<<<dim3(NGRP, B), 256, 0, stream>>>(
        featT, ptlist, starts, hist, w_bf,
        conv_b, gamma, beta, mean, var, wl, wlcnt, out);
    (void)in_sizes; (void)n_in; (void)out_size;
}